// Round 9
// baseline (148.621 us; speedup 1.0000x reference)
//
#include <hip/hip_runtime.h>
#include <math.h>

#define TLEN 2048
#define T2   4096
#define H2   2048
#define NBLK 512
#define EPS32 1.1920928955078125e-07

// agent-scope atomic load: always reads the coherent copy
__device__ __forceinline__ double ld_acc(const double* p){
  return __hip_atomic_load(p, __ATOMIC_RELAXED, __HIP_MEMORY_SCOPE_AGENT);
}

// ---- pure counter grid barrier (512 co-resident blocks; distinct counter per
//      use, zeroed host-side). NO threadfence (r4 lesson: ~26us each): the only
//      cross-block data is accs via agent-scope atomics. ----
__device__ __forceinline__ void gbar(unsigned* bar){
  __syncthreads();
  if (threadIdx.x == 0){
    __hip_atomic_fetch_add(bar, 1u, __ATOMIC_RELAXED, __HIP_MEMORY_SCOPE_AGENT);
    unsigned spins = 0;
    while (__hip_atomic_load(bar, __ATOMIC_RELAXED, __HIP_MEMORY_SCOPE_AGENT) < NBLK){
      if (++spins > (1u << 20)) break;        // safety valve: fail loud, not hung
      __builtin_amdgcn_s_sleep(8);
    }
  }
  __syncthreads();
}

// ---- 2048-pt complex FFT in LDS, 512 threads: 1 radix-2 + 5 radix-4 stages.
//      Result lands in src0 (6 stages = even ping-pong count). sgn=+1 fwd, -1 inv.
//      tw[p] = e^{-2pi i p/4096}. Stage loop stays `unroll 1` (r6 lesson: full
//      unroll -> VGPR blowout -> scratch spills). ----
__device__ __forceinline__ void fft2048(float2* src0, float2* dst0,
                                        const float2* __restrict__ tw, float sgn){
  const int tid = threadIdx.x;
  // radix-2 stage (L=1): 2 butterflies/thread; dst[2p],dst[2p+1] as one float4
  #pragma unroll
  for (int bf = 0; bf < 2; ++bf){
    int p = tid + (bf << 9);                  // 0..1023
    float2 a = src0[p], b = src0[p + 1024];
    float2 w = tw[2 * p];
    float wy = sgn * w.y;
    float dx = a.x - b.x, dy = a.y - b.y;
    *reinterpret_cast<float4*>(&dst0[2 * p]) =
      make_float4(a.x + b.x, a.y + b.y, dx * w.x - dy * wy, dx * wy + dy * w.x);
  }
  __syncthreads();
  // 5 radix-4 stages: L = 2,8,32,128,512; 1 butterfly/thread
  float2* src = dst0; float2* dst = src0;
  #pragma unroll 1
  for (int t = 0; t < 5; ++t){
    const int L = 2 << (2 * t);
    const int Lm = L - 1;
    {
      int idx = tid;                          // 0..511
      int q  = idx & Lm;
      int tb = idx - q;                       // p*L (<= 510)
      float2 a = src[idx];
      float2 b = src[idx + 512];
      float2 c = src[idx + 1024];
      float2 d = src[idx + 1536];
      float2 w1 = tw[2 * tb];
      float2 w2 = tw[4 * tb];
      float2 w3 = tw[6 * tb];
      float w1y = sgn * w1.y, w2y = sgn * w2.y, w3y = sgn * w3.y;
      float t0x = a.x + c.x, t0y = a.y + c.y;
      float t1x = a.x - c.x, t1y = a.y - c.y;
      float t2x = b.x + d.x, t2y = b.y + d.y;
      // fwd: -i*(b-d) = (y,-x); inv: +i*(b-d) = (-y,x)
      float t3x = sgn * (b.y - d.y);
      float t3y = -sgn * (b.x - d.x);
      float y0x = t0x + t2x, y0y = t0y + t2y;
      float y1x = t1x + t3x, y1y = t1y + t3y;
      float y2x = t0x - t2x, y2y = t0y - t2y;
      float y3x = t1x - t3x, y3y = t1y - t3y;
      int ob = q + (tb << 2);                 // q + 4*p*L
      dst[ob]         = make_float2(y0x, y0y);
      dst[ob + L]     = make_float2(y1x * w1.x - y1y * w1y, y1x * w1y + y1y * w1.x);
      dst[ob + 2 * L] = make_float2(y2x * w2.x - y2y * w2y, y2x * w2y + y2y * w2.x);
      dst[ob + 3 * L] = make_float2(y3x * w3.x - y3y * w3y, y3x * w3y + y3y * w3.x);
    }
    __syncthreads();
    float2* tt = src; src = dst; dst = tt;
  }
}

// ---- wave-64 shuffle sum ----
__device__ __forceinline__ double wred(double v){
  #pragma unroll
  for (int off = 32; off; off >>= 1) v += __shfl_down(v, off);
  return v;
}

// ---- reduce 9 named doubles (by value) -> atomicAdd (agent scope) into accs.
//      8 waves per 512-thread block. ----
__device__ __forceinline__ void red9(double a0, double a1, double a2, double a3,
                                     double a4, double a5, double a6, double a7,
                                     double a8, double* red, double* accs){
  const int tid = threadIdx.x, wave = tid >> 6, lane = tid & 63;
  double r;
  r = wred(a0); if (lane == 0) red[ 0 + wave] = r;
  r = wred(a1); if (lane == 0) red[ 8 + wave] = r;
  r = wred(a2); if (lane == 0) red[16 + wave] = r;
  r = wred(a3); if (lane == 0) red[24 + wave] = r;
  r = wred(a4); if (lane == 0) red[32 + wave] = r;
  r = wred(a5); if (lane == 0) red[40 + wave] = r;
  r = wred(a6); if (lane == 0) red[48 + wave] = r;
  r = wred(a7); if (lane == 0) red[56 + wave] = r;
  r = wred(a8); if (lane == 0) red[64 + wave] = r;
  __syncthreads();
  if (tid < 9){
    double s = red[tid*8+0] + red[tid*8+1] + red[tid*8+2] + red[tid*8+3]
             + red[tid*8+4] + red[tid*8+5] + red[tid*8+6] + red[tid*8+7];
    atomicAdd(&accs[tid], s);
  }
}

// ---- per-thread state is NAMED variables only; F lives in bufB ----
#define MODE_S(UXc, UYc, OMc, AFP, AP) {                       \
  float ox_ = sx - (UXc), oy_ = sy - (UYc);                    \
  float d_  = fj - (OMc);                                      \
  float den_ = 1.0f + 2000.0f * d_ * d_;                       \
  float nx_ = (Fx - ox_) / den_, ny_ = (Fy - oy_) / den_;      \
  float pw_ = nx_ * nx_ + ny_ * ny_;                           \
  AFP += (double)(fj * pw_);  AP += (double)pw_;               \
  float ddx_ = nx_ - (UXc), ddy_ = ny_ - (UYc);                \
  aD += (double)(ddx_ * ddx_ + ddy_ * ddy_);                   \
  (UXc) = nx_; (UYc) = ny_;                                    \
  sx = ox_ + nx_; sy = oy_ + ny_; }

#define BIN_S(PP, UX, UY) {                                    \
  int j = tid + ((PP) << 9);                                   \
  float2 Fv = bufB[j];                                         \
  float Fx = Fv.x, Fy = Fv.y;                                  \
  float fj = (float)j * (1.0f / 4096.0f);                      \
  float sx = UX.x + UX.y + UX.z + UX.w;                        \
  float sy = UY.x + UY.y + UY.z + UY.w;                        \
  MODE_S(UX.x, UY.x, om.x, aFP0, aP0)                          \
  MODE_S(UX.y, UY.y, om.y, aFP1, aP1)                          \
  MODE_S(UX.z, UY.z, om.z, aFP2, aP2)                          \
  MODE_S(UX.w, UY.w, om.w, aFP3, aP3) }

#define IT1(PP, UX, UY) { UX = make_float4(0.f,0.f,0.f,0.f);   \
                          UY = make_float4(0.f,0.f,0.f,0.f);   \
                          BIN_S(PP, UX, UY) }

// iter-5 mode-0 update; write U[j] (positive-half spectrum) into bufA
#define HERMU(PP, UX, UY) {                                    \
  int j = tid + ((PP) << 9);                                   \
  float vx, vy;                                                \
  if (act){                                                    \
    float2 Fv = bufB[j];                                       \
    float sx = UX.y + UX.z + UX.w;                             \
    float sy = UY.y + UY.z + UY.w;                             \
    float fj = (float)j * (1.0f / 4096.0f);                    \
    float dd = fj - om0;                                       \
    float den = 1.0f + 2000.0f * dd * dd;                      \
    vx = (Fv.x - sx) / den; vy = (Fv.y - sy) / den;            \
  } else { vx = UX.x; vy = UY.x; }                             \
  bufA[j] = make_float2(vx, vy); }

#define FOR4(M) M(0,ux0,uy0) M(1,ux1,uy1) M(2,ux2,uy2) M(3,ux3,uy3)

// ---- twiddle table (separate warm-up kernel: boundary = free coherence) ----
__global__ void k_tw(float2* __restrict__ tw){
  int p = blockIdx.x * 256 + threadIdx.x;    // 0..3071
  double a = -6.283185307179586 * (double)p / 4096.0;
  tw[p] = make_float2((float)cos(a), (float)sin(a));
}

// ==== half-size real-packed FFT pipeline, 512 threads/block ====
// r8 lesson: at 256 thr (2 waves/SIMD) ~70us of 93 was latency stall
// (VALUBusy 24%, HBM 1.5%). 512 thr x 512 blocks -> 2 blocks/CU ->
// 4 waves/SIMD; per-thread serial work halves. VGPR capped at 128 by
// waves_per_eu(4,4); LDS 32.5KB/block -> 65KB/CU fits.
__global__ void __attribute__((amdgpu_flat_work_group_size(512, 512),
                               amdgpu_waves_per_eu(4, 4)))
k_main(const float* __restrict__ x, const float2* __restrict__ tw,
       unsigned* __restrict__ bar, double* __restrict__ accs,
       float* __restrict__ xh, float* __restrict__ xl){
  __shared__ float2 bufA[H2];                 // 16 KiB
  __shared__ float2 bufB[H2];                 // 16 KiB
  __shared__ float somf[8];                   // omega/flag broadcast
  const int blk = blockIdx.x, tid = threadIdx.x;
  const int b = blk & 7, ch = blk >> 3;
  const float* xc = x + (size_t)b * TLEN * 64 + ch;

  // ---- pack z[m] = fM[2m] + i*fM[2m+1], 4 pts/thread (x read ONCE; middle
  //      values stashed for the epilogue) ----
  float xe0, xe1, xo0, xo1;
  {                                           // m=tid: n=2m<1024, s=1023-n
    int m = tid;
    bufA[m] = make_float2(xc[(size_t)(1023 - 2*m) * 64],
                          xc[(size_t)(1022 - 2*m) * 64]);
  }
  {                                           // m=tid+512: t=2m-1024 = 2*tid
    int t = 2 * tid;
    xe0 = xc[(size_t)t * 64];
    xo0 = xc[(size_t)(t + 1) * 64];
    bufA[tid + 512] = make_float2(xe0, xo0);
  }
  {                                           // m=tid+1024: t = 2*tid + 1024
    int t = 2 * tid + 1024;
    xe1 = xc[(size_t)t * 64];
    xo1 = xc[(size_t)(t + 1) * 64];
    bufA[tid + 1024] = make_float2(xe1, xo1);
  }
  {                                           // m=tid+1536: n>=3072, s=5119-n
    bufA[tid + 1536] = make_float2(xc[(size_t)(2047 - 2*tid) * 64],
                                   xc[(size_t)(2046 - 2*tid) * 64]);
  }
  __syncthreads();
  fft2048(bufA, bufB, tw, 1.0f);              // Z in bufA

  // ---- unpack to F[k] (k=0..2047) in bufB ----
  #pragma unroll
  for (int pp = 0; pp < 4; ++pp){
    int k = tid + (pp << 9);
    float2 A  = bufA[k];
    float2 Zm = bufA[(2048 - k) & 2047];
    float px = 0.5f * (A.x + Zm.x), py = 0.5f * (A.y - Zm.y);
    float qx = 0.5f * (A.x - Zm.x), qy = 0.5f * (A.y + Zm.y);
    float2 W = tw[k];
    bufB[k] = make_float2(px + W.x * qy + W.y * qx,
                          py - W.x * qx + W.y * qy);
  }
  __syncthreads();   // all Z reads done before red9 scribbles bufA

  float4 ux0, ux1, ux2, ux3;
  float4 uy0, uy1, uy2, uy3;
  float4 om = make_float4(0.0f, 0.125f, 0.25f, 0.375f);

  // iter 1 (u starts at 0)
  {
    double aFP0=0,aFP1=0,aFP2=0,aFP3=0,aP0=0,aP1=0,aP2=0,aP3=0,aD=0;
    FOR4(IT1)
    red9(aFP0,aFP1,aFP2,aFP3,aP0,aP1,aP2,aP3,aD, (double*)bufA, accs);
  }

  // ---- iters 2..4: omega via per-block LDS broadcast (9 agent loads/BLOCK) ----
  bool active = true;
  double* slot = accs;
  #pragma unroll 1
  for (int it = 0; it < 3; ++it){
    gbar(bar + it);
    if (tid < 4) somf[tid] = (float)(ld_acc(slot + tid) / ld_acc(slot + 4 + tid));
    if (tid == 7) somf[7] = (ld_acc(slot + 8) * (1.0/4096.0) + EPS32 > 5e-5) ? 1.f : 0.f;
    __syncthreads();
    if (active){
      if (somf[7] != 0.0f){
        om.x = somf[0]; om.y = somf[1]; om.z = somf[2]; om.w = somf[3];
      } else active = false;
    }
    if (active){
      double aFP0=0,aFP1=0,aFP2=0,aFP3=0,aP0=0,aP1=0,aP2=0,aP3=0,aD=0;
      FOR4(BIN_S)
      red9(aFP0,aFP1,aFP2,aFP3,aP0,aP1,aP2,aP3,aD, (double*)bufA, slot + 9);
    }
    slot += 9;
  }
  gbar(bar + 3);

  // ---- guarded iter-5 mode-0 update; U -> bufA; Z' -> bufB; IFFT ----
  if (tid == 0) somf[0] = (float)(ld_acc(slot) / ld_acc(slot + 4));
  if (tid == 7) somf[7] = (ld_acc(slot + 8) * (1.0/4096.0) + EPS32 > 5e-5) ? 1.f : 0.f;
  __syncthreads();
  {
    bool act = active && (somf[7] != 0.0f);
    float om0 = somf[0];
    FOR4(HERMU)                               // reads F (bufB), writes U (bufA)
    __syncthreads();
    #pragma unroll
    for (int pp = 0; pp < 4; ++pp){           // build Z' into bufB
      int k = tid + (pp << 9);
      float2 Zv;
      if (k == 0){
        float e = bufA[0].x + bufA[2047].x;   // Re U0 + Re U2047
        float o = bufA[0].x - bufA[2047].x;
        Zv = make_float2(e, o);
      } else {
        float2 A  = bufA[k];
        float2 Bm = bufA[2048 - k];           // U[2048-k]
        float ex = A.x + Bm.x, ey = A.y - Bm.y;   // A + conj(Bm)
        float dx = A.x - Bm.x, dy = A.y + Bm.y;   // A - conj(Bm)
        float2 W = tw[k];                     // O' = D * conj(W)
        float ox = dx * W.x + dy * W.y;
        float oy = dy * W.x - dx * W.y;
        Zv = make_float2(ex - oy, ey + ox);   // E' + i O'
      }
      bufB[k] = Zv;
    }
    __syncthreads();
    fft2048(bufB, bufA, tw, -1.0f);           // z' in bufB
  }

  // ---- epilogue: s[1024+t] pairs from z'[512..1535]; x from the stash ----
  {
    const float scale = 1.0f / 4096.0f;
    {                                         // m = 512+tid -> t0 = 2*tid
      float2 zv = bufB[512 + tid];
      int t0 = 2 * tid;
      size_t o0 = ((size_t)(b * TLEN + t0)) * 64 + ch;
      float l0 = zv.x * scale, l1 = zv.y * scale;
      xh[o0]      = xe0 - l0;  xl[o0]      = l0;
      xh[o0 + 64] = xo0 - l1;  xl[o0 + 64] = l1;
    }
    {                                         // m = 1024+tid -> t0 = 2*tid+1024
      float2 zv = bufB[1024 + tid];
      int t0 = 2 * tid + 1024;
      size_t o0 = ((size_t)(b * TLEN + t0)) * 64 + ch;
      float l0 = zv.x * scale, l1 = zv.y * scale;
      xh[o0]      = xe1 - l0;  xl[o0]      = l0;
      xh[o0 + 64] = xo1 - l1;  xl[o0 + 64] = l1;
    }
  }
}

extern "C" void kernel_launch(void* const* d_in, const int* in_sizes, int n_in,
                              void* d_out, int out_size, void* d_ws, size_t ws_size,
                              hipStream_t stream){
  const float* x = (const float*)d_in[0];
  float* out_xh = (float*)d_out;
  float* out_xl = out_xh + (size_t)8 * TLEN * 64;

  char* ws = (char*)d_ws;
  float2* tw   = (float2*)ws;                     // 24 KiB (3072 twiddles)
  char*   sync = ws + 32768;                      // barrier counters + accs
  unsigned* bar  = (unsigned*)sync;               // 16 counters (64 B)
  double*   accs = (double*)(sync + 128);         // 36 doubles

  hipMemsetAsync(sync, 0, 512, stream);           // zero bars + accs
  k_tw<<<12, 256, 0, stream>>>(tw);
  k_main<<<NBLK, 512, 0, stream>>>(x, tw, bar, accs, out_xh, out_xl);
}

// Round 10
// 137.220 us; speedup vs baseline: 1.0831x; 1.0831x over previous
//
#include <hip/hip_runtime.h>
#include <math.h>

#define TLEN 2048
#define T2   4096
#define H2   2048
#define NBLK 512
#define EPS32 1.1920928955078125e-07

// agent-scope atomic load: always reads the coherent copy
__device__ __forceinline__ double ld_acc(const double* p){
  return __hip_atomic_load(p, __ATOMIC_RELAXED, __HIP_MEMORY_SCOPE_AGENT);
}

// ---- pure counter grid barrier (512 co-resident blocks; distinct counter per
//      use). NO threadfence (r4 lesson: ~26us each): only cross-block data is
//      accs via agent-scope atomics. ----
__device__ __forceinline__ void gbar(unsigned* bar){
  __syncthreads();
  if (threadIdx.x == 0){
    __hip_atomic_fetch_add(bar, 1u, __ATOMIC_RELAXED, __HIP_MEMORY_SCOPE_AGENT);
    unsigned spins = 0;
    while (__hip_atomic_load(bar, __ATOMIC_RELAXED, __HIP_MEMORY_SCOPE_AGENT) < NBLK){
      if (++spins > (1u << 20)) break;        // safety valve: fail loud, not hung
      __builtin_amdgcn_s_sleep(8);
    }
  }
  __syncthreads();
}

// ---- radix-4 Stockham stages (256 thr, 2 butterflies/thread), twiddles in LDS.
//      Stage loop stays `unroll 1` (r6 lesson: full unroll -> scratch spills). ----
__device__ __forceinline__ void r4_stages(float2* src, float2* dst,
                                          const float2* twl, float sgn, int nst){
  const int tid = threadIdx.x;
  #pragma unroll 1
  for (int t = 0; t < nst; ++t){
    const int L = 2 << (2 * t);
    const int Lm = L - 1;
    #pragma unroll
    for (int bf = 0; bf < 2; ++bf){
      int idx = tid + (bf << 8);              // 0..511
      int q  = idx & Lm;
      int tb = idx - q;                       // p*L (<= 510)
      float2 a = src[idx];
      float2 b = src[idx + 512];
      float2 c = src[idx + 1024];
      float2 d = src[idx + 1536];
      float2 w1 = twl[2 * tb];
      float2 w2 = twl[4 * tb];
      float2 w3 = twl[6 * tb];
      float w1y = sgn * w1.y, w2y = sgn * w2.y, w3y = sgn * w3.y;
      float t0x = a.x + c.x, t0y = a.y + c.y;
      float t1x = a.x - c.x, t1y = a.y - c.y;
      float t2x = b.x + d.x, t2y = b.y + d.y;
      // fwd: -i*(b-d) = (y,-x); inv: +i*(b-d) = (-y,x)
      float t3x = sgn * (b.y - d.y);
      float t3y = -sgn * (b.x - d.x);
      float y0x = t0x + t2x, y0y = t0y + t2y;
      float y1x = t1x + t3x, y1y = t1y + t3y;
      float y2x = t0x - t2x, y2y = t0y - t2y;
      float y3x = t1x - t3x, y3y = t1y - t3y;
      int ob = q + (tb << 2);                 // q + 4*p*L
      dst[ob]         = make_float2(y0x, y0y);
      dst[ob + L]     = make_float2(y1x * w1.x - y1y * w1y, y1x * w1y + y1y * w1.x);
      dst[ob + 2 * L] = make_float2(y2x * w2.x - y2y * w2y, y2x * w2y + y2y * w2.x);
      dst[ob + 3 * L] = make_float2(y3x * w3.x - y3y * w3y, y3x * w3y + y3y * w3.x);
    }
    __syncthreads();
    float2* tt = src; src = dst; dst = tt;
  }
}

// ---- wave-64 shuffle sum ----
__device__ __forceinline__ double wred(double v){
  #pragma unroll
  for (int off = 32; off; off >>= 1) v += __shfl_down(v, off);
  return v;
}

// ---- reduce 9 named doubles (by value) -> atomicAdd (agent scope); 4 waves ----
__device__ __forceinline__ void red9(double a0, double a1, double a2, double a3,
                                     double a4, double a5, double a6, double a7,
                                     double a8, double* red, double* accs){
  const int tid = threadIdx.x, wave = tid >> 6, lane = tid & 63;
  double r;
  r = wred(a0); if (lane == 0) red[ 0 + wave] = r;
  r = wred(a1); if (lane == 0) red[ 4 + wave] = r;
  r = wred(a2); if (lane == 0) red[ 8 + wave] = r;
  r = wred(a3); if (lane == 0) red[12 + wave] = r;
  r = wred(a4); if (lane == 0) red[16 + wave] = r;
  r = wred(a5); if (lane == 0) red[20 + wave] = r;
  r = wred(a6); if (lane == 0) red[24 + wave] = r;
  r = wred(a7); if (lane == 0) red[28 + wave] = r;
  r = wred(a8); if (lane == 0) red[32 + wave] = r;
  __syncthreads();
  if (tid < 9)
    atomicAdd(&accs[tid], red[tid*4+0] + red[tid*4+1] + red[tid*4+2] + red[tid*4+3]);
}

// ---- per-thread state is NAMED variables only; F lives in bufB ----
#define MODE_S(UXc, UYc, OMc, AFP, AP) {                       \
  float ox_ = sx - (UXc), oy_ = sy - (UYc);                    \
  float d_  = fj - (OMc);                                      \
  float den_ = 1.0f + 2000.0f * d_ * d_;                       \
  float nx_ = (Fx - ox_) / den_, ny_ = (Fy - oy_) / den_;      \
  float pw_ = nx_ * nx_ + ny_ * ny_;                           \
  AFP += (double)(fj * pw_);  AP += (double)pw_;               \
  float ddx_ = nx_ - (UXc), ddy_ = ny_ - (UYc);                \
  aD += (double)(ddx_ * ddx_ + ddy_ * ddy_);                   \
  (UXc) = nx_; (UYc) = ny_;                                    \
  sx = ox_ + nx_; sy = oy_ + ny_; }

#define BIN_S(PP, UX, UY) {                                    \
  int j = tid + ((PP) << 8);                                   \
  float2 Fv = bufB[j];                                         \
  float Fx = Fv.x, Fy = Fv.y;                                  \
  float fj = (float)j * (1.0f / 4096.0f);                      \
  float sx = UX.x + UX.y + UX.z + UX.w;                        \
  float sy = UY.x + UY.y + UY.z + UY.w;                        \
  MODE_S(UX.x, UY.x, om.x, aFP0, aP0)                          \
  MODE_S(UX.y, UY.y, om.y, aFP1, aP1)                          \
  MODE_S(UX.z, UY.z, om.z, aFP2, aP2)                          \
  MODE_S(UX.w, UY.w, om.w, aFP3, aP3) }

#define IT1(PP, UX, UY) { UX = make_float4(0.f,0.f,0.f,0.f);   \
                          UY = make_float4(0.f,0.f,0.f,0.f);   \
                          BIN_S(PP, UX, UY) }

// iter-5 mode-0 update; write U[j] (positive-half spectrum) into bufA
#define HERMU(PP, UX, UY) {                                    \
  int j = tid + ((PP) << 8);                                   \
  float vx, vy;                                                \
  if (act){                                                    \
    float2 Fv = bufB[j];                                       \
    float sx = UX.y + UX.z + UX.w;                             \
    float sy = UY.y + UY.z + UY.w;                             \
    float fj = (float)j * (1.0f / 4096.0f);                    \
    float dd = fj - om0;                                       \
    float den = 1.0f + 2000.0f * dd * dd;                      \
    vx = (Fv.x - sx) / den; vy = (Fv.y - sy) / den;            \
  } else { vx = UX.x; vy = UY.x; }                             \
  bufA[j] = make_float2(vx, vy); }

#define FOR8(M) M(0,ux0,uy0) M(1,ux1,uy1) M(2,ux2,uy2) M(3,ux3,uy3) \
                M(4,ux4,uy4) M(5,ux5,uy5) M(6,ux6,uy6) M(7,ux7,uy7)

// fused forward radix-2 from packed registers (sgn=+1); writes float4 at bufB[2p]
#define R2F(BF, ZA, ZB) {                                      \
  int p = tid + ((BF) << 8);                                   \
  float2 w = twl[2 * p];                                       \
  float dx = ZA.x - ZB.x, dy = ZA.y - ZB.y;                    \
  *reinterpret_cast<float4*>(&bufB[2 * p]) =                   \
    make_float4(ZA.x + ZB.x, ZA.y + ZB.y,                      \
                dx * w.x - dy * w.y, dx * w.y + dy * w.x); }

// fused inverse LAST stage (L=512 => tb=0, twiddle-free); y1,y2 only
#define ILAST(IDX, Y1, Y2) {                                   \
  float2 a = bufA[IDX];                                        \
  float2 bb = bufA[(IDX) + 512];                               \
  float2 c = bufA[(IDX) + 1024];                               \
  float2 d = bufA[(IDX) + 1536];                               \
  float t1x = a.x - c.x, t1y = a.y - c.y;                      \
  float t3x = -(bb.y - d.y), t3y = (bb.x - d.x);               \
  Y1 = make_float2(t1x + t3x, t1y + t3y);                      \
  float t0x = a.x + c.x, t0y = a.y + c.y;                      \
  float t2x = bb.x + d.x, t2y = bb.y + d.y;                    \
  Y2 = make_float2(t0x - t2x, t0y - t2y); }

// ---- boot kernel: fp64-accurate twiddles + zero the sync area (replaces the
//      hipMemsetAsync dispatch; kernel boundary = free coherence for k_main) ----
__global__ void k_boot(float2* __restrict__ tw, unsigned* __restrict__ syncz){
  int p = blockIdx.x * 256 + threadIdx.x;     // 0..3071
  double a = -6.283185307179586 * (double)p / 4096.0;
  tw[p] = make_float2((float)cos(a), (float)sin(a));
  if (blockIdx.x == 0 && threadIdx.x < 128) syncz[threadIdx.x] = 0u;
}

// ==== half-size real-packed FFT pipeline, 256 thr (r9 occupancy experiment
// REFUTED: 2x waves => -17% perf; reverted). New vs r8: twiddles in LDS
// (removes ~70 global loads/thread inside barrier-locked FFT stages), forward
// radix-2 fused with pack (one LDS round-trip + barrier deleted), inverse last
// stage fused with epilogue (stores+barrier+reads deleted; tb=0 => no twiddle).
__global__ void __attribute__((amdgpu_flat_work_group_size(256, 256),
                               amdgpu_waves_per_eu(2, 2)))
k_main(const float* __restrict__ x, const float2* __restrict__ tw,
       unsigned* __restrict__ bar, double* __restrict__ accs,
       float* __restrict__ xh, float* __restrict__ xl){
  __shared__ float2 twl[3072];                // 24 KiB twiddles (LDS-resident)
  __shared__ float2 bufA[H2];                 // 16 KiB
  __shared__ float2 bufB[H2];                 // 16 KiB
  __shared__ float somf[8];                   // omega/flag broadcast
  const int tid = threadIdx.x;
  const int b = blockIdx.x & 7, ch = blockIdx.x >> 3;
  const float* xc = x + (size_t)b * TLEN * 64 + ch;

  // ---- stage twiddles to LDS (12 coalesced loads/thread) ----
  #pragma unroll
  for (int i = 0; i < 12; ++i)
    twl[tid + (i << 8)] = tw[tid + (i << 8)];

  // ---- pack z[m]=fM[2m]+i*fM[2m+1] into 8 registers (x read ONCE; z2..z5
  //      double as the epilogue's x stash) ----
  float2 z0, z1, z2, z3, z4, z5, z6, z7;
  z0 = make_float2(xc[(size_t)(1023 - 2*tid) * 64], xc[(size_t)(1022 - 2*tid) * 64]);
  z1 = make_float2(xc[(size_t)( 511 - 2*tid) * 64], xc[(size_t)( 510 - 2*tid) * 64]);
  { int t = 2*tid;        z2 = make_float2(xc[(size_t)t*64], xc[(size_t)(t+1)*64]); }
  { int t = 2*tid + 512;  z3 = make_float2(xc[(size_t)t*64], xc[(size_t)(t+1)*64]); }
  { int t = 2*tid + 1024; z4 = make_float2(xc[(size_t)t*64], xc[(size_t)(t+1)*64]); }
  { int t = 2*tid + 1536; z5 = make_float2(xc[(size_t)t*64], xc[(size_t)(t+1)*64]); }
  z6 = make_float2(xc[(size_t)(2047 - 2*tid) * 64], xc[(size_t)(2046 - 2*tid) * 64]);
  z7 = make_float2(xc[(size_t)(1535 - 2*tid) * 64], xc[(size_t)(1534 - 2*tid) * 64]);
  __syncthreads();                            // twl visible

  // ---- forward FFT: fused radix-2 from registers (pairs (m, m+1024)) ----
  R2F(0, z0, z4)  R2F(1, z1, z5)  R2F(2, z2, z6)  R2F(3, z3, z7)
  __syncthreads();
  r4_stages(bufB, bufA, twl, 1.0f, 5);        // Z in bufA

  // ---- unpack to F[k] (k=0..2047) in bufB ----
  #pragma unroll
  for (int pp = 0; pp < 8; ++pp){
    int k = tid + (pp << 8);
    float2 A  = bufA[k];
    float2 Zm = bufA[(2048 - k) & 2047];
    float px = 0.5f * (A.x + Zm.x), py = 0.5f * (A.y - Zm.y);
    float qx = 0.5f * (A.x - Zm.x), qy = 0.5f * (A.y + Zm.y);
    float2 W = twl[k];
    bufB[k] = make_float2(px + W.x * qy + W.y * qx,
                          py - W.x * qx + W.y * qy);
  }
  __syncthreads();   // all Z reads done before red9 scribbles bufA

  float4 ux0, ux1, ux2, ux3, ux4, ux5, ux6, ux7;
  float4 uy0, uy1, uy2, uy3, uy4, uy5, uy6, uy7;
  float4 om = make_float4(0.0f, 0.125f, 0.25f, 0.375f);

  // iter 1 (u starts at 0)
  {
    double aFP0=0,aFP1=0,aFP2=0,aFP3=0,aP0=0,aP1=0,aP2=0,aP3=0,aD=0;
    FOR8(IT1)
    red9(aFP0,aFP1,aFP2,aFP3,aP0,aP1,aP2,aP3,aD, (double*)bufA, accs);
  }

  // ---- iters 2..4: omega via per-block LDS broadcast ----
  bool active = true;
  double* slot = accs;
  #pragma unroll 1
  for (int it = 0; it < 3; ++it){
    gbar(bar + it);
    if (tid < 4) somf[tid] = (float)(ld_acc(slot + tid) / ld_acc(slot + 4 + tid));
    if (tid == 7) somf[7] = (ld_acc(slot + 8) * (1.0/4096.0) + EPS32 > 5e-5) ? 1.f : 0.f;
    __syncthreads();
    if (active){
      if (somf[7] != 0.0f){
        om.x = somf[0]; om.y = somf[1]; om.z = somf[2]; om.w = somf[3];
      } else active = false;
    }
    if (active){
      double aFP0=0,aFP1=0,aFP2=0,aFP3=0,aP0=0,aP1=0,aP2=0,aP3=0,aD=0;
      FOR8(BIN_S)
      red9(aFP0,aFP1,aFP2,aFP3,aP0,aP1,aP2,aP3,aD, (double*)bufA, slot + 9);
    }
    slot += 9;
  }
  gbar(bar + 3);

  // ---- guarded iter-5 mode-0 update; U -> bufA; Z' -> bufB; inverse FFT ----
  if (tid == 0) somf[0] = (float)(ld_acc(slot) / ld_acc(slot + 4));
  if (tid == 7) somf[7] = (ld_acc(slot + 8) * (1.0/4096.0) + EPS32 > 5e-5) ? 1.f : 0.f;
  __syncthreads();
  {
    bool act = active && (somf[7] != 0.0f);
    float om0 = somf[0];
    FOR8(HERMU)                               // reads F (bufB), writes U (bufA)
    __syncthreads();
    #pragma unroll
    for (int pp = 0; pp < 8; ++pp){           // build Z' into bufB
      int k = tid + (pp << 8);
      float2 Zv;
      if (k == 0){
        float e = bufA[0].x + bufA[2047].x;   // Re U0 + Re U2047
        float o = bufA[0].x - bufA[2047].x;
        Zv = make_float2(e, o);
      } else {
        float2 A  = bufA[k];
        float2 Bm = bufA[2048 - k];           // U[2048-k]
        float ex = A.x + Bm.x, ey = A.y - Bm.y;   // A + conj(Bm)
        float dx = A.x - Bm.x, dy = A.y + Bm.y;   // A - conj(Bm)
        float2 W = twl[k];                    // O' = D * conj(W)
        float ox = dx * W.x + dy * W.y;
        float oy = dy * W.x - dx * W.y;
        Zv = make_float2(ex - oy, ey + ox);   // E' + i O'
      }
      bufB[k] = Zv;
    }
    __syncthreads();
    // inverse radix-2 (reads bufB, writes bufA), sgn=-1
    #pragma unroll
    for (int bf = 0; bf < 4; ++bf){
      int p = tid + (bf << 8);
      float2 a = bufB[p], bb = bufB[p + 1024];
      float2 w = twl[2 * p];
      float dx = a.x - bb.x, dy = a.y - bb.y;
      *reinterpret_cast<float4*>(&bufA[2 * p]) =
        make_float4(a.x + bb.x, a.y + bb.y,
                    dx * w.x + dy * w.y, -dx * w.y + dy * w.x);
    }
    __syncthreads();
    r4_stages(bufA, bufB, twl, -1.0f, 4);     // stages L=2..128; result in bufA
  }

  // ---- fused last inverse stage + epilogue (all from registers) ----
  {
    const float scale = 1.0f / 4096.0f;
    float2 y1a, y2a, y1b, y2b;
    ILAST(tid,       y1a, y2a)                // y1 -> z'[512+tid],  y2 -> z'[1024+tid]
    ILAST(tid + 256, y1b, y2b)                // y1 -> z'[768+tid],  y2 -> z'[1280+tid]
    #define STOUT(YV, T0, ZS) {                                \
      size_t o0 = ((size_t)(b * TLEN + (T0))) * 64 + ch;       \
      float l0 = YV.x * scale, l1 = YV.y * scale;              \
      xh[o0]      = ZS.x - l0;  xl[o0]      = l0;              \
      xh[o0 + 64] = ZS.y - l1;  xl[o0 + 64] = l1; }
    STOUT(y1a, 2*tid,        z2)
    STOUT(y1b, 2*tid + 512,  z3)
    STOUT(y2a, 2*tid + 1024, z4)
    STOUT(y2b, 2*tid + 1536, z5)
  }
}

extern "C" void kernel_launch(void* const* d_in, const int* in_sizes, int n_in,
                              void* d_out, int out_size, void* d_ws, size_t ws_size,
                              hipStream_t stream){
  const float* x = (const float*)d_in[0];
  float* out_xh = (float*)d_out;
  float* out_xl = out_xh + (size_t)8 * TLEN * 64;

  char* ws = (char*)d_ws;
  float2* tw   = (float2*)ws;                     // 24 KiB (3072 twiddles)
  char*   sync = ws + 32768;                      // barrier counters + accs
  unsigned* bar  = (unsigned*)sync;               // 16 counters (64 B)
  double*   accs = (double*)(sync + 128);         // 36 doubles

  k_boot<<<12, 256, 0, stream>>>(tw, (unsigned*)sync);   // tw + zero sync area
  k_main<<<NBLK, 256, 0, stream>>>(x, tw, bar, accs, out_xh, out_xl);
}